// Round 5
// baseline (208.867 us; speedup 1.0000x reference)
//
#include <hip/hip_runtime.h>
#include <math.h>

#define N 4096
#define IN_F 256
#define OUT_F 512
#define H 8
#define D 64
#define NEG 0.2f
#define JC 2048  // j-chunk per block (grid.z = 2)

typedef __attribute__((ext_vector_type(8))) short bf16x8;
typedef __attribute__((ext_vector_type(4))) float f32x4;

__device__ __forceinline__ float leaky(float x) { return fmaxf(x, NEG * x); }

__device__ __forceinline__ unsigned short f2bf(float x) {
    union { float f; unsigned u; } v; v.f = x;
    unsigned r = v.u + 0x7fff + ((v.u >> 16) & 1);  // RNE
    return (unsigned short)(r >> 16);
}

// monotone float<->uint map for atomicMax-based float max
__device__ __forceinline__ unsigned fmap(float x) {
    union { float f; unsigned u; } v; v.f = x;
    return (v.u & 0x80000000u) ? ~v.u : (v.u | 0x80000000u);
}
__device__ __forceinline__ float funmap(unsigned m) {
    union { float f; unsigned u; } v;
    v.u = (m & 0x80000000u) ? (m & 0x7fffffffu) : ~m;
    return v.f;
}

// async 16B global->LDS DMA
__device__ __forceinline__ void dma16(const void* g, void* l) {
    __builtin_amdgcn_global_load_lds((const __attribute__((address_space(1))) void*)g,
                                     (__attribute__((address_space(3))) void*)l, 16, 0, 0);
}

// ---- K1: h = inp @ W^T per (i-tile, head). BK=64, register-prefetch double buffer.
__global__ __launch_bounds__(256) void k_gemm(const float* __restrict__ inp,
                                              const float* __restrict__ W,
                                              const float* __restrict__ a_left,
                                              unsigned short* __restrict__ hbT,
                                              float* __restrict__ s,
                                              unsigned* __restrict__ smaxU) {
    __shared__ float As[64][68];
    __shared__ float Bs[64][68];
    __shared__ unsigned short h_st[64][72];
    __shared__ float s_red[64];

    const int t = threadIdx.x;
    const int bi = blockIdx.x;
    const int head = blockIdx.y;
    const int ty = t >> 4, tx = t & 15;
    const int lr = t >> 2;
    const int cq = (t & 3) * 16;

    float4 pa[4], pb[4];
    auto loadrk = [&](int k0) {
        const float* ip = &inp[(size_t)(bi * 64 + lr) * IN_F + k0 + cq];
        const float* wp = &W[(size_t)(head * 64 + lr) * IN_F + k0 + cq];
#pragma unroll
        for (int q = 0; q < 4; ++q) {
            pa[q] = *(const float4*)&ip[q * 4];
            pb[q] = *(const float4*)&wp[q * 4];
        }
    };
    loadrk(0);

    float acc[4][4] = {};
    for (int k0 = 0; k0 < IN_F; k0 += 64) {
        __syncthreads();
#pragma unroll
        for (int q = 0; q < 4; ++q)
#pragma unroll
            for (int j = 0; j < 4; ++j) {
                As[cq + q * 4 + j][lr] = ((const float*)&pa[q])[j];
                Bs[cq + q * 4 + j][lr] = ((const float*)&pb[q])[j];
            }
        __syncthreads();
        if (k0 + 64 < IN_F) loadrk(k0 + 64);
#pragma unroll
        for (int k = 0; k < 64; ++k) {
            float4 a4 = *(const float4*)&As[k][ty * 4];
            float4 b4 = *(const float4*)&Bs[k][tx * 4];
            float a[4] = {a4.x, a4.y, a4.z, a4.w};
            float b[4] = {b4.x, b4.y, b4.z, b4.w};
#pragma unroll
            for (int r = 0; r < 4; ++r)
#pragma unroll
                for (int c = 0; c < 4; ++c) acc[r][c] = fmaf(a[r], b[c], acc[r][c]);
        }
    }

    float aL[4];
#pragma unroll
    for (int c = 0; c < 4; ++c) aL[c] = a_left[head * D + tx * 4 + c];
#pragma unroll
    for (int r = 0; r < 4; ++r) {
        float sp = acc[r][0] * aL[0] + acc[r][1] * aL[1] + acc[r][2] * aL[2] + acc[r][3] * aL[3];
        sp += __shfl_xor(sp, 1); sp += __shfl_xor(sp, 2);
        sp += __shfl_xor(sp, 4); sp += __shfl_xor(sp, 8);
        if (tx == 0) {
            s[head * N + bi * 64 + ty * 4 + r] = sp;
            s_red[ty * 4 + r] = sp;
        }
    }
    __syncthreads();
    if (t < 64) {
        float m = s_red[t];
        for (int off = 32; off; off >>= 1) m = fmaxf(m, __shfl_down(m, off, 64));
        if (t == 0) atomicMax(&smaxU[head], fmap(m));
    }

#pragma unroll
    for (int r = 0; r < 4; ++r) {
        ushort4 v;
        v.x = f2bf(acc[r][0]); v.y = f2bf(acc[r][1]);
        v.z = f2bf(acc[r][2]); v.w = f2bf(acc[r][3]);
        *(ushort4*)&h_st[ty * 4 + r][tx * 4] = v;
    }
    __syncthreads();
    {
        const int d = t >> 2, iq = (t & 3) * 16;
        unsigned short us[16];
#pragma unroll
        for (int k = 0; k < 16; ++k) us[k] = h_st[iq + k][d];
        unsigned short* dst = &hbT[((size_t)(head * D + d)) * N + bi * 64 + iq];
#pragma unroll
        for (int q = 0; q < 4; ++q) {
            ushort4 v = {us[q * 4 + 0], us[q * 4 + 1], us[q * 4 + 2], us[q * 4 + 3]};
            *(ushort4*)&dst[q * 4] = v;
        }
    }
}

// ---- K2a (big path): fused rowmax + A->bf16 conversion
__global__ __launch_bounds__(256) void k_prep(const float* __restrict__ A,
                                              unsigned short* __restrict__ Abf,
                                              float* __restrict__ rmax) {
    int i = blockIdx.x;
    const float* row = &A[(size_t)i * N];
    unsigned short* dst = &Abf[(size_t)i * N];
    float m = -1e30f;
    for (int j = threadIdx.x * 4; j < N; j += 256 * 4) {
        float4 v = *(const float4*)&row[j];
        m = fmaxf(fmaxf(fmaxf(m, v.x), fmaxf(v.y, v.z)), v.w);
        ushort4 b = {f2bf(v.x), f2bf(v.y), f2bf(v.z), f2bf(v.w)};
        *(ushort4*)&dst[j] = b;
    }
    for (int off = 32; off; off >>= 1) m = fmaxf(m, __shfl_down(m, off, 64));
    __shared__ float red[4];
    if ((threadIdx.x & 63) == 0) red[threadIdx.x >> 6] = m;
    __syncthreads();
    if (threadIdx.x == 0) rmax[i] = fmaxf(fmaxf(red[0], red[1]), fmaxf(red[2], red[3]));
}

// ---- K2b (fallback path): per-row max of A only
__global__ __launch_bounds__(256) void k_rowmax(const float* __restrict__ A,
                                                float* __restrict__ rmax) {
    int i = blockIdx.x;
    const float* row = &A[(size_t)i * N];
    float m = -1e30f;
    for (int j = threadIdx.x * 4; j < N; j += 256 * 4) {
        float4 v = *(const float4*)&row[j];
        m = fmaxf(fmaxf(fmaxf(m, v.x), fmaxf(v.y, v.z)), v.w);
    }
    for (int off = 32; off; off >>= 1) m = fmaxf(m, __shfl_down(m, off, 64));
    __shared__ float red[4];
    if ((threadIdx.x & 63) == 0) red[threadIdx.x >> 6] = m;
    __syncthreads();
    if (threadIdx.x == 0) rmax[i] = fmaxf(fmaxf(red[0], red[1]), fmaxf(red[2], red[3]));
}

// ---- K3 (big path): fused attention, 128 i-rows/block, double-buffered DMA LDS,
// bf16 A, Z via ones-MFMA. Block = (128 i, head, j-half): grid 32 x 8 x 2.
__global__ __launch_bounds__(256, 2) void k_attn_big(const unsigned short* __restrict__ Abf,
                                                     const unsigned short* __restrict__ hbT,
                                                     const float* __restrict__ s,
                                                     const unsigned* __restrict__ smaxU,
                                                     const float* __restrict__ rmax,
                                                     float* __restrict__ out,
                                                     float* __restrict__ Z) {
    __shared__ unsigned short A_st[2][128 * 64];  // 2 x 16 KB, slot-swizzled
    __shared__ unsigned short hT_st[2][64 * 64];  // 2 x 8 KB, slot-swizzled
    __shared__ float s_ch[JC];                    // 8 KB

    const int t = threadIdx.x;
    const int i0 = blockIdx.x * 128;
    const int head = blockIdx.y;
    const int j0 = blockIdx.z * JC;
    const int lane = t & 63, wave = t >> 6, quad = lane >> 4, li = lane & 15;

#pragma unroll
    for (int q = 0; q < 2; ++q) {
        int idx = q * 256 + t;
        *(float4*)&s_ch[idx * 4] = *(const float4*)&s[head * N + j0 + idx * 4];
    }
    const float smx = funmap(smaxU[head]);
    float s_i[2], negmb[2];
#pragma unroll
    for (int is = 0; is < 2; ++is) {
        int row = i0 + wave * 32 + is * 16 + li;
        float sv = s[head * N + row];
        s_i[is] = sv;
        negmb[is] = -(leaky(sv + smx) + rmax[row]);
    }

    // DMA descriptors: global side carries the XOR swizzle (u' holds j8 = u'^(row&7))
    const unsigned short* gA[4]; unsigned short* lA[2][4];
#pragma unroll
    for (int q = 0; q < 4; ++q) {
        int slot = q * 256 + t, row = slot >> 3, u = slot & 7;
        gA[q] = Abf + (size_t)(i0 + row) * N + j0 + ((u ^ (row & 7)) << 3);
        lA[0][q] = &A_st[0][slot * 8];
        lA[1][q] = &A_st[1][slot * 8];
    }
    const unsigned short* gH[2]; unsigned short* lH[2][2];
#pragma unroll
    for (int q = 0; q < 2; ++q) {
        int slot = q * 256 + t, d = slot >> 3, u = slot & 7;
        gH[q] = hbT + (size_t)head * D * N + (size_t)d * N + j0 + ((u ^ (d & 7)) << 3);
        lH[0][q] = &hT_st[0][slot * 8];
        lH[1][q] = &hT_st[1][slot * 8];
    }

    f32x4 acc[2][4] = {};
    f32x4 accz[2] = {};
    bf16x8 onesb;
#pragma unroll
    for (int i = 0; i < 8; ++i) onesb[i] = 0x3F80;  // bf16 1.0

    // prologue: DMA tile 0 into buffer 0
#pragma unroll
    for (int q = 0; q < 4; ++q) dma16(gA[q], lA[0][q]);
#pragma unroll
    for (int q = 0; q < 2; ++q) dma16(gH[q], lH[0][q]);

    for (int tt = 0; tt < JC / 64; ++tt) {
        const int p = tt & 1;
        __syncthreads();  // drains DMA(tile tt) + all waves done with buf[p]
        if (tt + 1 < JC / 64) {
            const int ju = (tt + 1) * 64;
#pragma unroll
            for (int q = 0; q < 4; ++q) dma16(gA[q] + ju, lA[p ^ 1][q]);
#pragma unroll
            for (int q = 0; q < 2; ++q) dma16(gH[q] + ju, lH[p ^ 1][q]);
        }
        const int jt = tt * 64;
#pragma unroll
        for (int kh = 0; kh < 2; ++kh) {
            const int u0 = kh * 4 + quad;
            float4 s0 = *(const float4*)&s_ch[jt + kh * 32 + quad * 8];
            float4 s1 = *(const float4*)&s_ch[jt + kh * 32 + quad * 8 + 4];
            float sv[8] = {s0.x, s0.y, s0.z, s0.w, s1.x, s1.y, s1.z, s1.w};
            bf16x8 hf[4];
#pragma unroll
            for (int db = 0; db < 4; ++db) {
                int d = db * 16 + li;
                hf[db] = *(const bf16x8*)&hT_st[p][(d * 8 + (u0 ^ (d & 7))) * 8];
            }
#pragma unroll
            for (int is = 0; is < 2; ++is) {
                int r = wave * 32 + is * 16 + li;
                uint4 au = *(const uint4*)&A_st[p][(r * 8 + (u0 ^ (r & 7))) * 8];
                unsigned auv[4] = {au.x, au.y, au.z, au.w};
                union { bf16x8 v; unsigned u[4]; } P;
                const float si = s_i[is], nmb = negmb[is];
#pragma unroll
                for (int w = 0; w < 4; ++w) {
                    float aLo = __uint_as_float(auv[w] << 16);
                    float aHi = __uint_as_float(auv[w] & 0xffff0000u);
                    float t0 = si + sv[2 * w], t1 = si + sv[2 * w + 1];
                    float l0 = fmaxf(t0, NEG * t0), l1 = fmaxf(t1, NEG * t1);
                    float e0 = __expf(l0 + (aLo + nmb));
                    float e1 = __expf(l1 + (aHi + nmb));
                    unsigned r0 = __float_as_uint(e0) + 0x8000u;  // round-half-up bf16
                    unsigned r1 = __float_as_uint(e1) + 0x8000u;
                    P.u[w] = __builtin_amdgcn_perm(r1, r0, 0x07060302u);
                }
#pragma unroll
                for (int db = 0; db < 4; ++db)
                    acc[is][db] = __builtin_amdgcn_mfma_f32_16x16x32_bf16(P.v, hf[db], acc[is][db], 0, 0, 0);
                accz[is] = __builtin_amdgcn_mfma_f32_16x16x32_bf16(P.v, onesb, accz[is], 0, 0, 0);
            }
        }
    }

#pragma unroll
    for (int is = 0; is < 2; ++is) {
        int rowbase = i0 + wave * 32 + is * 16 + quad * 4;
#pragma unroll
        for (int r = 0; r < 4; ++r) {
            float* op = &out[(size_t)(rowbase + r) * OUT_F + head * D];
#pragma unroll
            for (int db = 0; db < 4; ++db) atomicAdd(&op[db * 16 + li], acc[is][db][r]);
        }
        if (li == 0) {
#pragma unroll
            for (int r = 0; r < 4; ++r) atomicAdd(&Z[head * N + rowbase + r], accz[is][r]);
        }
    }
}

// ---- K3 fallback (R4's proven k_attn): 64 i-rows, single-buffered DMA
__global__ __launch_bounds__(256, 4) void k_attn_f(const float* __restrict__ A,
                                                   const unsigned short* __restrict__ hbT,
                                                   const float* __restrict__ s,
                                                   const unsigned* __restrict__ smaxU,
                                                   const float* __restrict__ rmax,
                                                   float* __restrict__ out,
                                                   float* __restrict__ Z) {
    __shared__ float A_stf[64 * 16 * 4];
    __shared__ unsigned short hT_stf[64 * 8 * 8];
    __shared__ float s_ch[JC];

    const int t = threadIdx.x;
    const int i0 = blockIdx.x * 64;
    const int head = blockIdx.y;
    const int j0 = blockIdx.z * JC;
    const int lane = t & 63, wave = t >> 6, quad = lane >> 4, li = lane & 15;
    const int iw = wave * 16;
    const int myrow = i0 + iw + li;

#pragma unroll
    for (int q = 0; q < 2; ++q) {
        int idx = q * 256 + t;
        *(float4*)&s_ch[idx * 4] = *(const float4*)&s[head * N + j0 + idx * 4];
    }
    const float s_i = s[head * N + myrow];
    const float mb = leaky(s_i + funmap(smaxU[head])) + rmax[myrow];

    const float* gA[4]; void* lA[4];
#pragma unroll
    for (int q = 0; q < 4; ++q) {
        int slot = q * 256 + t;
        int r = slot >> 4, c4p = slot & 15;
        int c4 = c4p ^ (r & 7);
        gA[q] = &A[(size_t)(i0 + r) * N + j0 + c4 * 4];
        lA[q] = (void*)&A_stf[slot * 4];
    }
    const unsigned short* gH[2]; void* lH[2];
#pragma unroll
    for (int q = 0; q < 2; ++q) {
        int slot = q * 256 + t;
        int r = slot >> 3, u = slot & 7;
        int uc = u ^ (r & 7);
        gH[q] = &hbT[(size_t)head * D * N + (size_t)r * N + j0 + uc * 8];
        lH[q] = (void*)&hT_stf[slot * 8];
    }

    f32x4 acc[4] = {{0, 0, 0, 0}, {0, 0, 0, 0}, {0, 0, 0, 0}, {0, 0, 0, 0}};
    float zsum = 0.f;

    for (int jt = 0; jt < JC; jt += 64) {
        __syncthreads();
#pragma unroll
        for (int q = 0; q < 4; ++q) dma16(gA[q] + jt, lA[q]);
#pragma unroll
        for (int q = 0; q < 2; ++q) dma16(gH[q] + jt, lH[q]);
        __syncthreads();

#pragma unroll
        for (int kh = 0; kh < 2; ++kh) {
            const int u0 = kh * 8 + quad * 2;
            const int sw = li & 7;
            float4 a0 = *(const float4*)&A_stf[((iw + li) * 16 + (u0 ^ sw)) * 4];
            float4 a1 = *(const float4*)&A_stf[((iw + li) * 16 + ((u0 + 1) ^ sw)) * 4];
            const int jl = kh * 32 + quad * 8;
            float4 s0 = *(const float4*)&s_ch[jt + jl];
            float4 s1 = *(const float4*)&s_ch[jt + jl + 4];
            float av[8] = {a0.x, a0.y, a0.z, a0.w, a1.x, a1.y, a1.z, a1.w};
            float sv[8] = {s0.x, s0.y, s0.z, s0.w, s1.x, s1.y, s1.z, s1.w};
            union { bf16x8 v; unsigned u[4]; } P;
#pragma unroll
            for (int p = 0; p < 4; ++p) {
                float x0 = s_i + sv[2 * p + 0];
                float x1 = s_i + sv[2 * p + 1];
                float w0 = __expf(fmaxf(x0, NEG * x0) + (av[2 * p + 0] - mb));
                float w1 = __expf(fmaxf(x1, NEG * x1) + (av[2 * p + 1] - mb));
                zsum += w0 + w1;
                P.u[p] = ((unsigned)f2bf(w1) << 16) | (unsigned)f2bf(w0);
            }
#pragma unroll
            for (int db = 0; db < 4; ++db) {
                int slotH = (db * 16 + li) * 8 + ((kh * 4 + quad) ^ sw);
                bf16x8 hf = *(const bf16x8*)&hT_stf[slotH * 8];
                acc[db] = __builtin_amdgcn_mfma_f32_16x16x32_bf16(P.v, hf, acc[db], 0, 0, 0);
            }
        }
    }

    zsum += __shfl_xor(zsum, 16);
    zsum += __shfl_xor(zsum, 32);
    if (quad == 0) atomicAdd(&Z[head * N + myrow], zsum);

#pragma unroll
    for (int r = 0; r < 4; ++r) {
        float* op = &out[(size_t)(i0 + iw + quad * 4 + r) * OUT_F + head * D];
#pragma unroll
        for (int db = 0; db < 4; ++db) atomicAdd(&op[db * 16 + li], acc[db][r]);
    }
}

// ---- K4: normalize
__global__ __launch_bounds__(256) void k_norm(float* __restrict__ out,
                                              const float* __restrict__ Z) {
    int idx = blockIdx.x * 256 + threadIdx.x;
    int i = idx >> 9, hd = idx & 511, hh = hd >> 6;
    out[idx] = out[idx] / Z[hh * N + i];
}

extern "C" void kernel_launch(void* const* d_in, const int* in_sizes, int n_in,
                              void* d_out, int out_size, void* d_ws, size_t ws_size,
                              hipStream_t stream) {
    const float* inp = (const float*)d_in[0];
    const float* A = (const float*)d_in[1];
    const float* W = (const float*)d_in[2];
    const float* a_left = (const float*)d_in[3];
    float* out = (float*)d_out;

    // ws: hbT 4MB | s 128KB | Z 128KB | smaxU 32B | rmax 16KB | (5MB:) Abf 32MB
    unsigned short* hbT = (unsigned short*)d_ws;
    float* s = (float*)((char*)d_ws + (size_t)H * D * N * 2);
    float* Z = s + (size_t)H * N;
    unsigned* smaxU = (unsigned*)(Z + (size_t)H * N);
    float* rmax = (float*)(smaxU + 8);
    unsigned short* Abf = (unsigned short*)((char*)d_ws + ((size_t)5 << 20));
    const bool big = ws_size >= (((size_t)5 << 20) + (size_t)N * N * 2);

    hipMemsetAsync(out, 0, (size_t)N * OUT_F * sizeof(float), stream);
    hipMemsetAsync(Z, 0, (size_t)H * N * sizeof(float) + 8 * sizeof(unsigned), stream);

    k_gemm<<<dim3(N / 64, H), 256, 0, stream>>>(inp, W, a_left, hbT, s, smaxU);
    if (big) {
        k_prep<<<dim3(N), 256, 0, stream>>>(A, Abf, rmax);
        k_attn_big<<<dim3(N / 128, H, N / JC), 256, 0, stream>>>(Abf, hbT, s, smaxU, rmax, out, Z);
    } else {
        k_rowmax<<<dim3(N), 256, 0, stream>>>(A, rmax);
        k_attn_f<<<dim3(N / 64, H, N / JC), 256, 0, stream>>>(A, hbT, s, smaxU, rmax, out, Z);
    }
    k_norm<<<dim3(N * OUT_F / 256), 256, 0, stream>>>(out, Z);
}